// Round 7
// baseline (36.233 us; speedup 1.0000x reference)
//
#include <hip/hip_runtime.h>
#include <stdint.h>

// ACOLayer: reproduce JAX's sampling exactly.
//   u = jax.random.uniform(key(42), (32, 4096, 16), f32)
//   idx[b,i,a] = searchsorted(cdf_row_i, u[b,i,a]) clamped; -1 where a >= x[b,i]
// RNG: jax_threefry_partitionable=True stream:
//   bits[i] = o0 ^ o1, (o0,o1) = threefry2x32(key=(0,42), counter=(0, i))
//   u = bitcast((bits>>9)|0x3f800000) - 1.0f
//
// Round-7 structure: 1024 persistent blocks (4/CU, fully resident) x 4 rows,
// double-buffered LDS with ASYNC global->LDS prefetch (global_load_lds,
// width 16B). Counted s_waitcnt vmcnt(4) + raw s_barrier keeps next-row loads
// in flight across all barriers (never vmcnt(0) mid-loop) -> HBM stays busy
// while scan/search run. Threefry in the prefetch shadow. Segmented chunk
// ownership (float4 slot t+256c) -> conflict-free b128 LDS reads/writes.

#define N_IN    4096
#define N_OUT   4096
#define BS      32
#define MAX_A   16
#define THREADS 256
#define HALF    1048576u  /* 16 * N_IN * MAX_A */
#define RPB     4         /* rows per block */
#define GRID    (N_IN / RPB)

typedef __attribute__((address_space(1))) const uint32_t u32_g;
typedef __attribute__((address_space(3))) uint32_t u32_l;

__device__ __forceinline__ uint32_t rotl32(uint32_t x, uint32_t r) {
    return (x << r) | (x >> (32u - r));
}

// Threefry-2x32, 20 rounds, key (0, 42) — jax.random.key(42)
__device__ __forceinline__ void threefry2x32_42(uint32_t x0, uint32_t x1,
                                                uint32_t& o0, uint32_t& o1) {
    const uint32_t k0 = 0u, k1 = 42u;
    const uint32_t k2 = k0 ^ k1 ^ 0x1BD11BDAu;
    x0 += k0; x1 += k1;
#define TF_R(r) { x0 += x1; x1 = rotl32(x1, (r)); x1 ^= x0; }
    TF_R(13) TF_R(15) TF_R(26) TF_R(6)
    x0 += k1; x1 += k2 + 1u;
    TF_R(17) TF_R(29) TF_R(16) TF_R(24)
    x0 += k2; x1 += k0 + 2u;
    TF_R(13) TF_R(15) TF_R(26) TF_R(6)
    x0 += k0; x1 += k1 + 3u;
    TF_R(17) TF_R(29) TF_R(16) TF_R(24)
    x0 += k1; x1 += k2 + 4u;
    TF_R(13) TF_R(15) TF_R(26) TF_R(6)
    x0 += k2; x1 += k0 + 5u;
#undef TF_R
    o0 = x0; o1 = x1;
}

__device__ __forceinline__ float bits_to_uniform(uint32_t b) {
    uint32_t f = (b >> 9) | 0x3f800000u;
    float r;
    __builtin_memcpy(&r, &f, 4);
    return r - 1.0f;
}

// lgkm drain + raw barrier: makes LDS writes visible WITHOUT draining vmcnt
// (so async prefetch stays in flight across the barrier).
__device__ __forceinline__ void lds_barrier() {
    asm volatile("s_waitcnt lgkmcnt(0)" ::: "memory");
    __builtin_amdgcn_s_barrier();
}

// async prefetch of one 16KB row into LDS, linear layout, 4 instrs/thread.
// wave wid covers floats [1024*wid, 1024*(wid+1)); instr c covers 256 floats.
__device__ __forceinline__ void prefetch_row(const float* __restrict__ wrow,
                                             float* buf, int wid, int lane) {
#if defined(__has_builtin) && __has_builtin(__builtin_amdgcn_global_load_lds)
    const float* g = wrow + wid * 1024 + lane * 4;
    float* l = buf + wid * 1024;            // wave-uniform base; HW adds lane*16
    #pragma unroll
    for (int c = 0; c < 4; ++c) {
        __builtin_amdgcn_global_load_lds((u32_g*)(g + c * 256),
                                         (u32_l*)(l + c * 256), 16, 0, 0);
    }
#else
    // fallback: synchronous staging (slower, correct)
    #pragma unroll
    for (int c = 0; c < 4; ++c) {
        float4 v = *(const float4*)(wrow + wid * 1024 + c * 256 + lane * 4);
        *(float4*)(buf + wid * 1024 + c * 256 + lane * 4) = v;
    }
#endif
}

// fixed 12-step lower_bound on linear LDS cdf
__device__ __forceinline__ int lower_bound_cdf(const float* cdf, float tval) {
    int lo = 0, hi = N_OUT;
    #pragma unroll
    for (int it = 0; it < 12; ++it) {
        int mid = (lo + hi) >> 1;
        if (cdf[mid] < tval) lo = mid + 1; else hi = mid;
    }
    return lo < N_OUT ? lo : N_OUT - 1;
}

__global__ __launch_bounds__(THREADS)
void aco_pipe_kernel(const int* __restrict__ x,
                     const float* __restrict__ w,
                     int* __restrict__ out) {
    __shared__ __align__(16) float buf[2][N_OUT];   // 32 KB double buffer
    __shared__ float4 wsum4[4];
    __shared__ int    xc[RPB][BS];

    const int g    = blockIdx.x;
    const int t    = threadIdx.x;
    const int lane = t & 63;
    const int wid  = t >> 6;
    const int bb   = t >> 4;   // 0..15
    const int aa   = t & 15;

    // prologue: x columns for all 4 rows (strided, tiny) + prefetch row 0
    if (t < RPB * BS) {
        const int r = t >> 5, b = t & 31;
        xc[r][b] = x[b * N_IN + (g + GRID * r)];
    }
    prefetch_row(w + (size_t)g * N_OUT, buf[0], wid, lane);

    #pragma unroll
    for (int k = 0; k < RPB; ++k) {
        const int row = g + GRID * k;

        // 1. issue next row's async prefetch (stays in flight across barriers)
        if (k + 1 < RPB)
            prefetch_row(w + (size_t)(row + GRID) * N_OUT, buf[(k + 1) & 1],
                         wid, lane);

        // 2. threefry in the prefetch shadow (pure VALU, no memory deps)
        const uint32_t j0 = (uint32_t)(bb * (N_IN * MAX_A) + row * MAX_A + aa);
        uint32_t o0, o1, p0, p1;
        threefry2x32_42(0u, j0, o0, o1);
        threefry2x32_42(0u, j0 + HALF, p0, p1);
        const float u0 = bits_to_uniform(o0 ^ o1);
        const float u1 = bits_to_uniform(p0 ^ p1);

        // 3. wait for row k's own-wave prefetch only (allow the 4 newest
        //    VMEM ops = next row's prefetch to stay outstanding), then barrier
        if (k + 1 < RPB) asm volatile("s_waitcnt vmcnt(4)" ::: "memory");
        else             asm volatile("s_waitcnt vmcnt(0)" ::: "memory");
        lds_barrier();                     // B1: row k fully in buf[k&1]

        // 4. read own chunks (conflict-free b128), scan
        float* cb = buf[k & 1];
        const float4 v0 = ((const float4*)cb)[t];        // seg0: floats 4t..4t+3
        const float4 v1 = ((const float4*)cb)[t + 256];
        const float4 v2 = ((const float4*)cb)[t + 512];
        const float4 v3 = ((const float4*)cb)[t + 768];

        float4 s;
        s.x = v0.x + v0.y + v0.z + v0.w;
        s.y = v1.x + v1.y + v1.z + v1.w;
        s.z = v2.x + v2.y + v2.z + v2.w;
        s.w = v3.x + v3.y + v3.z + v3.w;

        float4 incl = s;
        #pragma unroll
        for (int d = 1; d < 64; d <<= 1) {
            float nx = __shfl_up(incl.x, d, 64);
            float ny = __shfl_up(incl.y, d, 64);
            float nz = __shfl_up(incl.z, d, 64);
            float nw = __shfl_up(incl.w, d, 64);
            if (lane >= d) { incl.x += nx; incl.y += ny; incl.z += nz; incl.w += nw; }
        }
        if (lane == 63) wsum4[wid] = incl;
        lds_barrier();                     // B2: wave totals visible

        const float4 W0 = wsum4[0], W1 = wsum4[1], W2 = wsum4[2], W3 = wsum4[3];
        const float T0 = W0.x + W1.x + W2.x + W3.x;
        const float T1 = W0.y + W1.y + W2.y + W3.y;
        const float T2 = W0.z + W1.z + W2.z + W3.z;
        const float T3 = W0.w + W1.w + W2.w + W3.w;
        const float total = T0 + T1 + T2 + T3;
        float4 wp = make_float4(0.f, 0.f, 0.f, 0.f);
        if (wid > 0) { wp.x += W0.x; wp.y += W0.y; wp.z += W0.z; wp.w += W0.w; }
        if (wid > 1) { wp.x += W1.x; wp.y += W1.y; wp.z += W1.z; wp.w += W1.w; }
        if (wid > 2) { wp.x += W2.x; wp.y += W2.y; wp.z += W2.z; wp.w += W2.w; }
        const float E0 = 0.f          + wp.x + (incl.x - s.x);
        const float E1 = T0           + wp.y + (incl.y - s.y);
        const float E2 = T0 + T1      + wp.z + (incl.z - s.z);
        const float E3 = T0 + T1 + T2 + wp.w + (incl.w - s.w);

        // 5. write cumsum back over own slots (no cross-thread hazard)
        {
            float4 c; float r;
            r = E0 + v0.x; c.x = r; r += v0.y; c.y = r; r += v0.z; c.z = r; r += v0.w; c.w = r;
            ((float4*)cb)[t] = c;
            r = E1 + v1.x; c.x = r; r += v1.y; c.y = r; r += v1.z; c.z = r; r += v1.w; c.w = r;
            ((float4*)cb)[t + 256] = c;
            r = E2 + v2.x; c.x = r; r += v2.y; c.y = r; r += v2.z; c.z = r; r += v2.w; c.w = r;
            ((float4*)cb)[t + 512] = c;
            r = E3 + v3.x; c.x = r; r += v3.y; c.y = r; r += v3.z; c.z = r; r += v3.w; c.w = r;
            ((float4*)cb)[t + 768] = c;
        }
        lds_barrier();                     // B3: full cdf visible

        // 6. search + store
        const int idx0 = lower_bound_cdf(cb, u0 * total);
        const int idx1 = lower_bound_cdf(cb, u1 * total);
        out[j0]        = (aa < xc[k][bb])      ? idx0 : -1;
        out[j0 + HALF] = (aa < xc[k][bb + 16]) ? idx1 : -1;

        // 7. end barrier: all waves done reading cb before the NEXT iteration
        //    prefetches into it (buf[(k+2)&1] == cb)
        lds_barrier();                     // B4
    }
}

extern "C" void kernel_launch(void* const* d_in, const int* in_sizes, int n_in,
                              void* d_out, int out_size, void* d_ws, size_t ws_size,
                              hipStream_t stream) {
    // select inputs by size (robust to ordering):
    //   x: 32*4096 int32; weights: 4096*4096 f32
    const int*   x;
    const float* w;
    if (in_sizes[0] == BS * N_IN) { x = (const int*)d_in[0]; w = (const float*)d_in[1]; }
    else                          { x = (const int*)d_in[1]; w = (const float*)d_in[0]; }
    aco_pipe_kernel<<<GRID, THREADS, 0, stream>>>(x, w, (int*)d_out);
}

// Round 8
// 20.909 us; speedup vs baseline: 1.7329x; 1.7329x over previous
//
#include <hip/hip_runtime.h>
#include <stdint.h>

// ACOLayer: reproduce JAX's sampling exactly.
//   u = jax.random.uniform(key(42), (32, 4096, 16), f32)
//   idx[b,i,a] = searchsorted(cdf_row_i, u[b,i,a]) clamped; -1 where a >= x[b,i]
// RNG: jax_threefry_partitionable=True stream:
//   bits[i] = o0 ^ o1, (o0,o1) = threefry2x32(key=(0,42), counter=(0, i))
//   u = bitcast((bits>>9)|0x3f800000) - 1.0f
// Search: unnormalized cumsum, target u*total.
//
// Round 8 = round 3 (best, 21.35us) with ONE change: LDS padding +1 word per
// 32 (padi = j + (j>>5)) instead of +4 per 64. Binary-search probe sets are
// power-of-2 strided; with 32 banks the old padding left mid-level strides
// (64/128/256 words) on 4-8 banks -> 8-32-way conflicts. +1/32 spreads every
// stride 4..2048 across >=8 banks (worst ~4-way). Cost: cumsum write-back is
// 16 ds_write_b32 (banks (16t+(t>>1))%32 = all 32 -> conflict-free) instead
// of 4 ds_write_b128.

#define N_IN    4096
#define N_OUT   4096
#define BS      32
#define MAX_A   16
#define THREADS 256
#define HALF    1048576u  /* 16 * N_IN * MAX_A */

// +1 word per 32: search-optimal bank spread for power-of-2 strides
__device__ __forceinline__ int padi(int j) { return j + (j >> 5); }

__device__ __forceinline__ uint32_t rotl32(uint32_t x, uint32_t r) {
    return (x << r) | (x >> (32u - r));
}

// Threefry-2x32, 20 rounds, key (0, 42) — jax.random.key(42)
__device__ __forceinline__ void threefry2x32_42(uint32_t x0, uint32_t x1,
                                                uint32_t& o0, uint32_t& o1) {
    const uint32_t k0 = 0u, k1 = 42u;
    const uint32_t k2 = k0 ^ k1 ^ 0x1BD11BDAu;
    x0 += k0; x1 += k1;
#define TF_R(r) { x0 += x1; x1 = rotl32(x1, (r)); x1 ^= x0; }
    TF_R(13) TF_R(15) TF_R(26) TF_R(6)
    x0 += k1; x1 += k2 + 1u;
    TF_R(17) TF_R(29) TF_R(16) TF_R(24)
    x0 += k2; x1 += k0 + 2u;
    TF_R(13) TF_R(15) TF_R(26) TF_R(6)
    x0 += k0; x1 += k1 + 3u;
    TF_R(17) TF_R(29) TF_R(16) TF_R(24)
    x0 += k1; x1 += k2 + 4u;
    TF_R(13) TF_R(15) TF_R(26) TF_R(6)
    x0 += k2; x1 += k0 + 5u;
#undef TF_R
    o0 = x0; o1 = x1;
}

__device__ __forceinline__ float bits_to_uniform(uint32_t b) {
    uint32_t f = (b >> 9) | 0x3f800000u;
    float r;
    __builtin_memcpy(&r, &f, 4);
    return r - 1.0f;
}

// fixed 12-step lower_bound on padded LDS cdf (no divergence)
__device__ __forceinline__ int lower_bound_cdf(const float* cdf, float tval) {
    int lo = 0, hi = N_OUT;
    #pragma unroll
    for (int it = 0; it < 12; ++it) {   // 4096 = 2^12
        int mid = (lo + hi) >> 1;
        if (cdf[padi(mid)] < tval) lo = mid + 1; else hi = mid;
    }
    return lo < N_OUT ? lo : N_OUT - 1;
}

__global__ __launch_bounds__(THREADS)
void aco_sample_kernel(const int* __restrict__ x,
                       const float* __restrict__ w,
                       int* __restrict__ out) {
    __shared__ float cdf[N_OUT + (N_OUT >> 5)];  // 4224 floats, +1/32 padded
    __shared__ float wsum[4];
    __shared__ int   xc[BS];

    const int row  = blockIdx.x;
    const int t    = threadIdx.x;
    const int lane = t & 63;
    const int wid  = t >> 6;

    // ---- stage 16 weights directly into registers (4x float4) ----
    const float4* wrow = (const float4*)(w + (size_t)row * N_OUT);
    float4 v0 = wrow[t * 4 + 0];
    float4 v1 = wrow[t * 4 + 1];
    float4 v2 = wrow[t * 4 + 2];
    float4 v3 = wrow[t * 4 + 3];

    if (t < BS) xc[t] = x[t * N_IN + row];

    // ---- local inclusive scan of 16 values in registers ----
    float loc[16];
    {
        float s = 0.f;
        s += v0.x; loc[0]  = s;  s += v0.y; loc[1]  = s;
        s += v0.z; loc[2]  = s;  s += v0.w; loc[3]  = s;
        s += v1.x; loc[4]  = s;  s += v1.y; loc[5]  = s;
        s += v1.z; loc[6]  = s;  s += v1.w; loc[7]  = s;
        s += v2.x; loc[8]  = s;  s += v2.y; loc[9]  = s;
        s += v2.z; loc[10] = s;  s += v2.w; loc[11] = s;
        s += v3.x; loc[12] = s;  s += v3.y; loc[13] = s;
        s += v3.z; loc[14] = s;  s += v3.w; loc[15] = s;
    }
    const float my_total = loc[15];

    // ---- wave-level inclusive scan of per-thread totals (register shuffles) ----
    float incl = my_total;
    #pragma unroll
    for (int d = 1; d < 64; d <<= 1) {
        float n = __shfl_up(incl, d, 64);
        if (lane >= d) incl += n;
    }
    if (lane == 63) wsum[wid] = incl;
    __syncthreads();   // B1: wsum visible

    const float4 ws = *(const float4*)wsum;
    const float total = ws.x + ws.y + ws.z + ws.w;
    float wprefix = 0.f;
    if (wid > 0) wprefix += ws.x;
    if (wid > 1) wprefix += ws.y;
    if (wid > 2) wprefix += ws.z;
    const float chunk_prefix = wprefix + incl - my_total;  // exclusive prefix of my 16

    // ---- write unnormalized cumsum to LDS (16 scalar writes, banks spread) ----
    {
        const int base = t * 16;
        #pragma unroll
        for (int m = 0; m < 16; ++m)
            cdf[padi(base + m)] = chunk_prefix + loc[m];
    }
    __syncthreads();   // B2: full cdf visible

    // ---- two draws per thread: (b, row, a) and (b+16, row, a) ----
    const int b = t >> 4;
    const int a = t & 15;
    const uint32_t j0 = (uint32_t)(b * (N_IN * MAX_A) + row * MAX_A + a);
    const uint32_t j1 = j0 + HALF;

    uint32_t o0, o1, p0, p1;
    threefry2x32_42(0u, j0, o0, o1);
    threefry2x32_42(0u, j1, p0, p1);
    const float t0 = bits_to_uniform(o0 ^ o1) * total;
    const float t1 = bits_to_uniform(p0 ^ p1) * total;

    const int idx0 = lower_bound_cdf(cdf, t0);
    const int idx1 = lower_bound_cdf(cdf, t1);

    out[j0] = (a < xc[b])      ? idx0 : -1;
    out[j1] = (a < xc[b + 16]) ? idx1 : -1;
}

extern "C" void kernel_launch(void* const* d_in, const int* in_sizes, int n_in,
                              void* d_out, int out_size, void* d_ws, size_t ws_size,
                              hipStream_t stream) {
    // select inputs by size (robust to ordering):
    //   x: 32*4096 int32; weights: 4096*4096 f32
    const int*   x;
    const float* w;
    if (in_sizes[0] == BS * N_IN) { x = (const int*)d_in[0]; w = (const float*)d_in[1]; }
    else                          { x = (const int*)d_in[1]; w = (const float*)d_in[0]; }
    aco_sample_kernel<<<N_IN, THREADS, 0, stream>>>(x, w, (int*)d_out);
}